// Round 5
// baseline (429.000 us; speedup 1.0000x reference)
//
#include <hip/hip_runtime.h>
#include <hip/hip_bf16.h>
#include <math.h>
#include <stdint.h>

#define BB 2
#define SS 2048
#define DD 512
#define HH 8
#define NTOK (BB*SS)      // 4096 tokens
#define NQKV (3*HH*DD)    // 12288
#define BHD  (HH*DD)      // 4096
#define NBH  (BB*HH)      // 16
#define NTILE 136         // tri(16): causal 128x128 tiles per (b,h)

typedef __attribute__((ext_vector_type(8))) short short8v;
typedef __attribute__((ext_vector_type(4))) float floatx4;

__device__ __forceinline__ unsigned short f2bf(float f) {
  unsigned int u = __builtin_bit_cast(unsigned int, f);
  u = (u + 0x7FFFu + ((u >> 16) & 1u)) >> 16;   // RNE
  return (unsigned short)u;
}
__device__ __forceinline__ float bf2f(unsigned short s) {
  unsigned int u = ((unsigned int)s) << 16;
  return __builtin_bit_cast(float, u);
}
__device__ __forceinline__ void async16(const void* g, void* l) {
  __builtin_amdgcn_global_load_lds(
      (const __attribute__((address_space(1))) unsigned int*)g,
      (__attribute__((address_space(3))) unsigned int*)l, 16, 0, 0);
}

// ---------------- prep: q -> bf16 ----------------
__global__ void k_convert_q(const float* __restrict__ q, unsigned short* __restrict__ qbf) {
  int i = (blockIdx.x * 256 + threadIdx.x) * 4;
  const float4 v = *(const float4*)&q[i];
  ushort4 o;
  o.x = f2bf(v.x); o.y = f2bf(v.y); o.z = f2bf(v.z); o.w = f2bf(v.w);
  *(ushort4*)&qbf[i] = o;
}

// ---------------- prep: RoPE table rope[dpair][s] = {cos, sin} (f32) ----------------
__global__ void k_rope_tab(float* __restrict__ rope) {
  const int idx = blockIdx.x * 256 + threadIdx.x;   // dp*2048 + s
  const int dp = idx >> 11, s = idx & 2047;
  const float inv = exp2f(-13.287712379549449f * (1.0f/256.0f) * (float)dp);
  float sn, cs;
  __sincosf((float)s * inv, &sn, &cs);
  rope[(size_t)idx * 2]     = cs;
  rope[(size_t)idx * 2 + 1] = sn;
}

// ---------------- prep: transpose weights to B^T bf16 (Wq pre-scaled by 1/sqrt(512)) ----------------
__global__ void k_prep_w(const float* __restrict__ Wq, const float* __restrict__ Wk,
                         const float* __restrict__ Wv, const float* __restrict__ Wo,
                         unsigned short* __restrict__ Wcat, unsigned short* __restrict__ Wot) {
  __shared__ float t[32][33];
  const int z = blockIdx.z;
  const float* in; unsigned short* out; int inLD, outLD;
  float sc = 1.0f;
  if (z < 24) {
    int tsel = z / 8, h = z % 8;
    const float* w = (tsel == 0) ? Wq : (tsel == 1) ? Wk : Wv;
    if (tsel == 0) sc = 0.044194173824159216f;   // 1/sqrt(512) folded into Wq
    in = w + (size_t)h * DD * DD;
    out = Wcat + ((size_t)tsel * BHD + (size_t)h * DD) * DD;
    inLD = DD; outLD = DD;
  } else {
    int k = z - 24;
    in = Wo + (size_t)k * DD * DD;
    out = Wot + (size_t)k * DD;
    inLD = DD; outLD = BHD;
  }
  const int tx = threadIdx.x, ty = threadIdx.y;
  const int bx = blockIdx.x * 32, by = blockIdx.y * 32;
  for (int kk = 0; kk < 4; ++kk)
    t[ty + 8*kk][tx] = in[(size_t)(by + ty + 8*kk) * inLD + bx + tx];
  __syncthreads();
  for (int kk = 0; kk < 4; ++kk)
    out[(size_t)(bx + ty + 8*kk) * outLD + by + tx] = f2bf(t[tx][ty + 8*kk] * sc);
}

// ---------------- GEMM1: QKV projection + table-RoPE epilogue (BK=32) ----------------
__global__ __launch_bounds__(256)
void k_qkv(const unsigned short* __restrict__ Abf, const unsigned short* __restrict__ Bt,
           const float* __restrict__ rope,
           unsigned short* __restrict__ Qr, unsigned short* __restrict__ Kr,
           unsigned short* __restrict__ Vt) {
  __shared__ short As[128*32];
  __shared__ short Bs[128*32];
  const int tid = threadIdx.x;
  const int m0 = blockIdx.x * 128;
  const int n0 = blockIdx.y * 128;
  const int wave = tid >> 6, lane = tid & 63, qd = lane >> 4, c = lane & 15;
  const int wm = (wave >> 1) * 64, wn = (wave & 1) * 64;
  floatx4 acc[4][4] = {};
  const int e0 = tid * 8;
  const int e1 = e0 + 2048;
  const int r0 = e0 >> 5, c0 = e0 & 31, r1 = e1 >> 5, c1 = e1 & 31;
  for (int k0 = 0; k0 < 512; k0 += 32) {
    __syncthreads();
    async16(&Abf[(size_t)(m0 + r0) * 512 + k0 + c0], &As[e0]);
    async16(&Abf[(size_t)(m0 + r1) * 512 + k0 + c1], &As[e1]);
    async16(&Bt [(size_t)(n0 + r0) * 512 + k0 + c0], &Bs[e0]);
    async16(&Bt [(size_t)(n0 + r1) * 512 + k0 + c1], &Bs[e1]);
    __syncthreads();
    short8v a[4], bfr[4];
    for (int mt = 0; mt < 4; ++mt) a[mt]   = *(const short8v*)&As[(wm + mt*16 + c)*32 + qd*8];
    for (int nt = 0; nt < 4; ++nt) bfr[nt] = *(const short8v*)&Bs[(wn + nt*16 + c)*32 + qd*8];
    for (int mt = 0; mt < 4; ++mt)
      for (int nt = 0; nt < 4; ++nt)
        acc[mt][nt] = __builtin_amdgcn_mfma_f32_16x16x32_bf16(a[mt], bfr[nt], acc[mt][nt], 0, 0, 0);
  }
  const int tsel = n0 >> 12;
  const int h = (n0 >> 9) & 7;
  const int bat = m0 >> 11;
  const int bh = bat * HH + h;
  const int dloc = (n0 & 511) + wn;
  if (tsel < 2) {
    unsigned short* dst = (tsel == 0) ? Qr : Kr;
    for (int nt = 0; nt < 4; ++nt) {
      const int d = dloc + nt*16 + c;
      const unsigned int sgn = (d & 1) ? 0u : 0x80000000u;  // even d: res = v*cs - p*sn
      const size_t rb = (size_t)(d >> 1) * (SS * 2);
      for (int mt = 0; mt < 4; ++mt) {
        const int mrow = (m0 & 2047) + wm + mt*16 + qd*4;
        const float4 t0 = *(const float4*)&rope[rb + (size_t)mrow * 2];      // cs0,sn0,cs1,sn1
        const float4 t1 = *(const float4*)&rope[rb + (size_t)mrow * 2 + 4];  // cs2,sn2,cs3,sn3
        const float cs[4] = {t0.x, t0.z, t1.x, t1.z};
        const float sn[4] = {t0.y, t0.w, t1.y, t1.w};
        for (int r = 0; r < 4; ++r) {
          const float v = acc[mt][nt][r];
          float p = __shfl_xor(v, 1, 64);
          p = __builtin_bit_cast(float, __builtin_bit_cast(unsigned int, p) ^ sgn);
          const float res = fmaf(p, sn[r], v * cs[r]);
          dst[((size_t)bh * SS + mrow + r) * DD + d] = f2bf(res);
        }
      }
    }
  } else {
    for (int nt = 0; nt < 4; ++nt) {
      const int d = dloc + nt*16 + c;
      const size_t vbase = ((size_t)bh * DD + d) * SS;
      for (int mt = 0; mt < 4; ++mt) {
        const int s = (m0 & 2047) + wm + mt*16 + qd*4;
        ushort4 u;
        u.x = f2bf(acc[mt][nt][0]); u.y = f2bf(acc[mt][nt][1]);
        u.z = f2bf(acc[mt][nt][2]); u.w = f2bf(acc[mt][nt][3]);
        *(ushort4*)&Vt[vbase + s] = u;
      }
    }
  }
}

// ---------------- pass A: E = exp(S) panels (bf16, causal triangle) + row sums l_z ----------------
__global__ __launch_bounds__(256)
void k_scores(const unsigned short* __restrict__ Qr, const unsigned short* __restrict__ Kr,
              unsigned short* __restrict__ Eg, float* __restrict__ lsum) {
  __shared__ short UN[17408];   // union: As[2]+Bs[2] (32 KB) | ET 128x136 (34 KB)
  short* As0 = UN;
  short* As1 = UN + 4096;
  short* Bs0 = UN + 8192;
  short* Bs1 = UN + 12288;
  unsigned short* ET = (unsigned short*)UN;
  const int tid = threadIdx.x;
  const int bh = blockIdx.y;
  const int t = blockIdx.x;
  int zb = 0;
  while (((zb + 1) * (zb + 2)) / 2 <= t) ++zb;
  const int st = t - (zb * (zb + 1)) / 2;
  const int z0 = zb * 128, s0 = st * 128;
  const int wave = tid >> 6, lane = tid & 63, qd = lane >> 4, c = lane & 15;
  const int wm = (wave >> 1) * 64, wn = (wave & 1) * 64;
  const size_t qb = (size_t)bh * SS * DD;
  floatx4 acc[4][4] = {};
  const int e0 = tid * 8, e1 = e0 + 2048;
  const int r0 = e0 >> 5, c0 = e0 & 31, r1 = e1 >> 5, c1 = e1 & 31;
  for (int k0 = 0; k0 < 512; k0 += 64) {
    __syncthreads();
    async16(&Qr[qb + (size_t)(z0 + r0) * 512 + k0      + c0], &As0[e0]);
    async16(&Qr[qb + (size_t)(z0 + r1) * 512 + k0      + c1], &As0[e1]);
    async16(&Qr[qb + (size_t)(z0 + r0) * 512 + k0 + 32 + c0], &As1[e0]);
    async16(&Qr[qb + (size_t)(z0 + r1) * 512 + k0 + 32 + c1], &As1[e1]);
    async16(&Kr[qb + (size_t)(s0 + r0) * 512 + k0      + c0], &Bs0[e0]);
    async16(&Kr[qb + (size_t)(s0 + r1) * 512 + k0      + c1], &Bs0[e1]);
    async16(&Kr[qb + (size_t)(s0 + r0) * 512 + k0 + 32 + c0], &Bs1[e0]);
    async16(&Kr[qb + (size_t)(s0 + r1) * 512 + k0 + 32 + c1], &Bs1[e1]);
    __syncthreads();
    for (int kc = 0; kc < 2; ++kc) {
      const short* Asp = kc ? As1 : As0;
      const short* Bsp = kc ? Bs1 : Bs0;
      short8v a[4], bfr[4];
      for (int mt = 0; mt < 4; ++mt) a[mt]   = *(const short8v*)&Asp[(wm + mt*16 + c)*32 + qd*8];
      for (int nt = 0; nt < 4; ++nt) bfr[nt] = *(const short8v*)&Bsp[(wn + nt*16 + c)*32 + qd*8];
      for (int mt = 0; mt < 4; ++mt)
        for (int nt = 0; nt < 4; ++nt)
          acc[mt][nt] = __builtin_amdgcn_mfma_f32_16x16x32_bf16(a[mt], bfr[nt], acc[mt][nt], 0, 0, 0);
    }
  }
  const bool diag = (st == zb);
  for (int mt = 0; mt < 4; ++mt) {
    const int zl = wm + mt*16 + qd*4;
    float rs[4] = {0.f, 0.f, 0.f, 0.f};
    for (int nt = 0; nt < 4; ++nt) {
      const int sl = wn + nt*16 + c;
      for (int r = 0; r < 4; ++r) {
        float ev = __expf(acc[mt][nt][r]);
        if (diag && (sl > zl + r)) ev = 0.f;
        acc[mt][nt][r] = ev;
        rs[r] += ev;
      }
    }
    for (int off = 1; off < 16; off <<= 1)
      for (int r = 0; r < 4; ++r) rs[r] += __shfl_xor(rs[r], off, 64);
    if (c == 0)
      for (int r = 0; r < 4; ++r)
        atomicAdd(&lsum[(size_t)bh * SS + z0 + zl + r], rs[r]);
  }
  __syncthreads();
  for (int mt = 0; mt < 4; ++mt) {
    const int zl = wm + mt*16 + qd*4;
    for (int nt = 0; nt < 4; ++nt) {
      const int sl = wn + nt*16 + c;
      ushort4 u;
      u.x = f2bf(acc[mt][nt][0]); u.y = f2bf(acc[mt][nt][1]);
      u.z = f2bf(acc[mt][nt][2]); u.w = f2bf(acc[mt][nt][3]);
      *(ushort4*)&ET[sl * 136 + zl] = u;
    }
  }
  __syncthreads();
  const size_t tb = ((size_t)bh * NTILE + t) * 16384;
  for (int it = 0; it < 8; ++it) {
    const int e = it * 2048 + tid * 8;
    const int row = e >> 7, col = e & 127;
    *(short8v*)&Eg[tb + row * 128 + col] = *(const short8v*)&ET[row * 136 + col];
  }
}

// ---------------- scale V by 1/l_z in place: Vs[d][z] = V^T[d][z] / l[z] ----------------
__global__ void k_vscale(unsigned short* __restrict__ Vt, const float* __restrict__ lsum) {
  const int idx = (blockIdx.x * 256 + threadIdx.x) * 8;
  const int z = idx & (SS - 1);
  const int bh = idx >> 20;
  short8v v = *(const short8v*)&Vt[idx];
  const float* lp = &lsum[(size_t)bh * SS + z];
  short8v o;
  for (int i = 0; i < 8; ++i)
    o[i] = (short)f2bf(bf2f((unsigned short)v[i]) / lp[i]);
  *(short8v*)&Vt[idx] = o;
}

// ---------------- pass B: out^T(128d x 128s) = sum_z Vs^T(d,z) E^T(s,z) — pure GEMM ----------------
__global__ __launch_bounds__(256)
void k_pv(const unsigned short* __restrict__ Eg, const unsigned short* __restrict__ Vs,
          unsigned short* __restrict__ Ocat) {
  __shared__ short Vl[2][128*32];
  __shared__ short El[2][128*32];
  const int tid = threadIdx.x;
  const int d0 = blockIdx.x * 128;
  const int st = blockIdx.y;          // s-tile of 128 (long blocks st=0 dispatch first per bh)
  const int bh = blockIdx.z;
  const int s0 = st * 128;
  const int bat = bh >> 3, h = bh & 7;
  const int wave = tid >> 6, lane = tid & 63, qd = lane >> 4, c = lane & 15;
  const int wm = (wave >> 1) * 64, wn = (wave & 1) * 64;
  const size_t vbb = (size_t)bh * DD * SS;
  floatx4 acc[4][4] = {};
  const int e = tid * 8;
  for (int zb = st; zb < 16; ++zb) {
    const size_t tb = ((size_t)bh * NTILE + (zb * (zb + 1)) / 2 + st) * 16384;
    for (int half = 0; half < 2; ++half) {
      const int zbase = zb * 128 + half * 64;
      __syncthreads();
      for (int i = 0; i < 4; ++i) {
        const int ee = e + i * 2048;
        const int kc = ee >> 12, row = (ee >> 5) & 127, col = ee & 31;
        async16(&Vs[vbb + (size_t)(d0 + row) * SS + zbase + kc * 32 + col], &Vl[kc][row * 32 + col]);
      }
      for (int i = 0; i < 4; ++i) {
        const int ee = e + i * 2048;
        const int kc = ee >> 12, row = (ee >> 5) & 127, col = ee & 31;
        async16(&Eg[tb + (size_t)row * 128 + half * 64 + kc * 32 + col], &El[kc][row * 32 + col]);
      }
      __syncthreads();
      for (int kc = 0; kc < 2; ++kc) {
        short8v a[4], b[4];
        for (int dt = 0; dt < 4; ++dt) a[dt] = *(const short8v*)&Vl[kc][(wm + dt*16 + c)*32 + qd*8];
        for (int nt = 0; nt < 4; ++nt) b[nt] = *(const short8v*)&El[kc][(wn + nt*16 + c)*32 + qd*8];
        for (int dt = 0; dt < 4; ++dt)
          for (int nt = 0; nt < 4; ++nt)
            acc[dt][nt] = __builtin_amdgcn_mfma_f32_16x16x32_bf16(a[dt], b[nt], acc[dt][nt], 0, 0, 0);
      }
    }
  }
  for (int nt = 0; nt < 4; ++nt) {
    const int sg = s0 + wn + nt*16 + c;
    const size_t ob = ((size_t)(bat * SS + sg)) * BHD + (size_t)h * DD + d0;
    for (int dt = 0; dt < 4; ++dt) {
      const int dloc = wm + dt*16 + qd*4;
      ushort4 u;
      u.x = f2bf(acc[dt][nt][0]); u.y = f2bf(acc[dt][nt][1]);
      u.z = f2bf(acc[dt][nt][2]); u.w = f2bf(acc[dt][nt][3]);
      *(ushort4*)&Ocat[ob + dloc] = u;
    }
  }
}

// ---------------- GEMM4: out += Ocat @ Wo, 128x128 tile, split-K=4, BK=64, f32 atomics ----------------
__global__ __launch_bounds__(256)
void k_oproj(const unsigned short* __restrict__ Ocat, const unsigned short* __restrict__ Wot,
             float* __restrict__ out) {
  __shared__ short As[2][128*32];
  __shared__ short Bs[2][128*32];
  const int tid = threadIdx.x;
  const int m0 = blockIdx.x * 128;
  const int n0 = blockIdx.y * 128;
  const int ks = blockIdx.z * 1024;
  const int wave = tid >> 6, lane = tid & 63, qd = lane >> 4, c = lane & 15;
  const int wm = (wave >> 1) * 64, wn = (wave & 1) * 64;
  floatx4 acc[4][4] = {};
  const int e0 = tid * 8, e1 = e0 + 2048;
  const int r0 = e0 >> 5, c0 = e0 & 31, r1 = e1 >> 5, c1 = e1 & 31;
  for (int k0 = ks; k0 < ks + 1024; k0 += 64) {
    __syncthreads();
    for (int kc = 0; kc < 2; ++kc) {
      const int kk = k0 + kc * 32;
      async16(&Ocat[(size_t)(m0 + r0) * BHD + kk + c0], &As[kc][e0]);
      async16(&Ocat[(size_t)(m0 + r1) * BHD + kk + c1], &As[kc][e1]);
      async16(&Wot [(size_t)(n0 + r0) * BHD + kk + c0], &Bs[kc][e0]);
      async16(&Wot [(size_t)(n0 + r1) * BHD + kk + c1], &Bs[kc][e1]);
    }
    __syncthreads();
    for (int kc = 0; kc < 2; ++kc) {
      short8v a[4], b[4];
      for (int mt = 0; mt < 4; ++mt) a[mt] = *(const short8v*)&As[kc][(wm + mt*16 + c)*32 + qd*8];
      for (int nt = 0; nt < 4; ++nt) b[nt] = *(const short8v*)&Bs[kc][(wn + nt*16 + c)*32 + qd*8];
      for (int mt = 0; mt < 4; ++mt)
        for (int nt = 0; nt < 4; ++nt)
          acc[mt][nt] = __builtin_amdgcn_mfma_f32_16x16x32_bf16(a[mt], b[nt], acc[mt][nt], 0, 0, 0);
    }
  }
  for (int mt = 0; mt < 4; ++mt) {
    const int m = m0 + wm + mt*16 + qd*4;
    for (int nt = 0; nt < 4; ++nt) {
      const int n = n0 + wn + nt*16 + c;
      for (int r = 0; r < 4; ++r)
        atomicAdd(&out[(size_t)(m + r) * DD + n], acc[mt][nt][r]);
    }
  }
}

extern "C" void kernel_launch(void* const* d_in, const int* in_sizes, int n_in,
                              void* d_out, int out_size, void* d_ws, size_t ws_size,
                              hipStream_t stream) {
  const float* q  = (const float*)d_in[0];
  const float* Wq = (const float*)d_in[1];
  const float* Wk = (const float*)d_in[2];
  const float* Wv = (const float*)d_in[3];
  const float* Wo = (const float*)d_in[4];

  // workspace layout with lifetime-based aliasing (peak ~176 MB)
  char* base = (char*)d_ws;
  unsigned short* Eg   = (unsigned short*)base;                       // 71,303,168 B
  unsigned short* qbf  = (unsigned short*)base;                       // overlay (dies after k_qkv)
  unsigned short* Wcat = (unsigned short*)(base + 4194304);           // overlay (dies after k_qkv)
  float*          rope = (float*)(base + 16777216);                   // 4 MB overlay (dies after k_qkv)
  char* p = base + 71303168;
  unsigned short* Wot  = (unsigned short*)p; p += 4194304;
  unsigned short* Qr   = (unsigned short*)p;
  unsigned short* Ocat = (unsigned short*)p; p += 33554432;           // overlays Qr (dead after k_scores)
  unsigned short* Kr   = (unsigned short*)p; p += 33554432;
  unsigned short* Vt   = (unsigned short*)p; p += 33554432;
  float*          lsum = (float*)p;

  hipMemsetAsync(lsum, 0, (size_t)NBH * SS * 4, stream);
  hipMemsetAsync(d_out, 0, (size_t)NTOK * DD * 4, stream);

  k_convert_q<<<NTOK*DD/1024, 256, 0, stream>>>(q, qbf);
  k_rope_tab<<<SS*256/256, 256, 0, stream>>>(rope);
  k_prep_w<<<dim3(16,16,32), dim3(32,8), 0, stream>>>(Wq, Wk, Wv, Wo, Wcat, Wot);
  k_qkv<<<dim3(32,96), 256, 0, stream>>>(qbf, Wcat, rope, Qr, Kr, Vt);
  k_scores<<<dim3(NTILE,16), 256, 0, stream>>>(Qr, Kr, Eg, lsum);
  k_vscale<<<NBH*DD*SS/(256*8), 256, 0, stream>>>(Vt, lsum);
  k_pv<<<dim3(4,16,16), 256, 0, stream>>>(Eg, Vt, Ocat);
  k_oproj<<<dim3(32,4,4), 256, 0, stream>>>(Ocat, Wot, (float*)d_out);
}

// Round 6
// 419.147 us; speedup vs baseline: 1.0235x; 1.0235x over previous
//
#include <hip/hip_runtime.h>
#include <hip/hip_bf16.h>
#include <math.h>
#include <stdint.h>

#define BB 2
#define SS 2048
#define DD 512
#define HH 8
#define NTOK (BB*SS)      // 4096 tokens
#define NQKV (3*HH*DD)    // 12288
#define BHD  (HH*DD)      // 4096
#define NBH  (BB*HH)      // 16
#define NTILE 136         // tri(16): causal 128x128 tiles per (b,h)

typedef __attribute__((ext_vector_type(8))) short short8v;
typedef __attribute__((ext_vector_type(4))) float floatx4;

__device__ __forceinline__ unsigned short f2bf(float f) {
  unsigned int u = __builtin_bit_cast(unsigned int, f);
  u = (u + 0x7FFFu + ((u >> 16) & 1u)) >> 16;   // RNE
  return (unsigned short)u;
}
__device__ __forceinline__ float bf2f(unsigned short s) {
  unsigned int u = ((unsigned int)s) << 16;
  return __builtin_bit_cast(float, u);
}
__device__ __forceinline__ void async16(const void* g, void* l) {
  __builtin_amdgcn_global_load_lds(
      (const __attribute__((address_space(1))) unsigned int*)g,
      (__attribute__((address_space(3))) unsigned int*)l, 16, 0, 0);
}

// ---------------- prep: q -> bf16 ----------------
__global__ void k_convert_q(const float* __restrict__ q, unsigned short* __restrict__ qbf) {
  int i = (blockIdx.x * 256 + threadIdx.x) * 4;
  const float4 v = *(const float4*)&q[i];
  ushort4 o;
  o.x = f2bf(v.x); o.y = f2bf(v.y); o.z = f2bf(v.z); o.w = f2bf(v.w);
  *(ushort4*)&qbf[i] = o;
}

// ---------------- prep: RoPE table rope[dpair][s] = {cos, sin} (f32) ----------------
__global__ void k_rope_tab(float* __restrict__ rope) {
  const int idx = blockIdx.x * 256 + threadIdx.x;   // dp*2048 + s
  const int dp = idx >> 11, s = idx & 2047;
  const float inv = exp2f(-13.287712379549449f * (1.0f/256.0f) * (float)dp);
  float sn, cs;
  __sincosf((float)s * inv, &sn, &cs);
  rope[(size_t)idx * 2]     = cs;
  rope[(size_t)idx * 2 + 1] = sn;
}

// ---------------- prep: transpose weights to B^T bf16 (Wq pre-scaled by 1/sqrt(512)) ----------------
__global__ void k_prep_w(const float* __restrict__ Wq, const float* __restrict__ Wk,
                         const float* __restrict__ Wv, const float* __restrict__ Wo,
                         unsigned short* __restrict__ Wcat, unsigned short* __restrict__ Wot) {
  __shared__ float t[32][33];
  const int z = blockIdx.z;
  const float* in; unsigned short* out; int inLD, outLD;
  float sc = 1.0f;
  if (z < 24) {
    int tsel = z / 8, h = z % 8;
    const float* w = (tsel == 0) ? Wq : (tsel == 1) ? Wk : Wv;
    if (tsel == 0) sc = 0.044194173824159216f;   // 1/sqrt(512) folded into Wq
    in = w + (size_t)h * DD * DD;
    out = Wcat + ((size_t)tsel * BHD + (size_t)h * DD) * DD;
    inLD = DD; outLD = DD;
  } else {
    int k = z - 24;
    in = Wo + (size_t)k * DD * DD;
    out = Wot + (size_t)k * DD;
    inLD = DD; outLD = BHD;
  }
  const int tx = threadIdx.x, ty = threadIdx.y;
  const int bx = blockIdx.x * 32, by = blockIdx.y * 32;
  for (int kk = 0; kk < 4; ++kk)
    t[ty + 8*kk][tx] = in[(size_t)(by + ty + 8*kk) * inLD + bx + tx];
  __syncthreads();
  for (int kk = 0; kk < 4; ++kk)
    out[(size_t)(bx + ty + 8*kk) * outLD + by + tx] = f2bf(t[tx][ty + 8*kk] * sc);
}

// ---------------- GEMM1: QKV projection, 128x256 tile (32 MFMA/wave/barrier), table-RoPE epilogue ----------------
__global__ __launch_bounds__(256, 2)
void k_qkv(const unsigned short* __restrict__ Abf, const unsigned short* __restrict__ Bt,
           const float* __restrict__ rope,
           unsigned short* __restrict__ Qr, unsigned short* __restrict__ Kr,
           unsigned short* __restrict__ Vt) {
  __shared__ short As[128*32];   //  8 KB
  __shared__ short Bs[256*32];   // 16 KB
  const int tid = threadIdx.x;
  const int m0 = blockIdx.x * 128;
  const int n0 = blockIdx.y * 256;
  const int wave = tid >> 6, lane = tid & 63, qd = lane >> 4, c = lane & 15;
  const int wm = (wave >> 1) * 64, wn = (wave & 1) * 128;
  floatx4 acc[4][8] = {};
  const int e0 = tid * 8;
  const int r0 = e0 >> 5, c0 = e0 & 31;   // r0 in [0,64)
  for (int k0 = 0; k0 < 512; k0 += 32) {
    __syncthreads();
    async16(&Abf[(size_t)(m0 + r0      ) * 512 + k0 + c0], &As[e0]);
    async16(&Abf[(size_t)(m0 + r0 +  64) * 512 + k0 + c0], &As[e0 + 2048]);
    async16(&Bt [(size_t)(n0 + r0      ) * 512 + k0 + c0], &Bs[e0]);
    async16(&Bt [(size_t)(n0 + r0 +  64) * 512 + k0 + c0], &Bs[e0 + 2048]);
    async16(&Bt [(size_t)(n0 + r0 + 128) * 512 + k0 + c0], &Bs[e0 + 4096]);
    async16(&Bt [(size_t)(n0 + r0 + 192) * 512 + k0 + c0], &Bs[e0 + 6144]);
    __syncthreads();
    short8v a[4], bfr[8];
    for (int mt = 0; mt < 4; ++mt) a[mt]   = *(const short8v*)&As[(wm + mt*16 + c)*32 + qd*8];
    for (int nt = 0; nt < 8; ++nt) bfr[nt] = *(const short8v*)&Bs[(wn + nt*16 + c)*32 + qd*8];
    for (int mt = 0; mt < 4; ++mt)
      for (int nt = 0; nt < 8; ++nt)
        acc[mt][nt] = __builtin_amdgcn_mfma_f32_16x16x32_bf16(a[mt], bfr[nt], acc[mt][nt], 0, 0, 0);
  }
  const int tsel = n0 >> 12;
  const int h = (n0 >> 9) & 7;
  const int bat = m0 >> 11;
  const int bh = bat * HH + h;
  const int dloc = (n0 & 511) + wn;
  if (tsel < 2) {
    unsigned short* dst = (tsel == 0) ? Qr : Kr;
    for (int nt = 0; nt < 8; ++nt) {
      const int d = dloc + nt*16 + c;
      const unsigned int sgn = (d & 1) ? 0u : 0x80000000u;  // even d: res = v*cs - p*sn
      const size_t rb = (size_t)(d >> 1) * (SS * 2);
      for (int mt = 0; mt < 4; ++mt) {
        const int mrow = (m0 & 2047) + wm + mt*16 + qd*4;
        const float4 t0 = *(const float4*)&rope[rb + (size_t)mrow * 2];      // cs0,sn0,cs1,sn1
        const float4 t1 = *(const float4*)&rope[rb + (size_t)mrow * 2 + 4];  // cs2,sn2,cs3,sn3
        const float cs[4] = {t0.x, t0.z, t1.x, t1.z};
        const float sn[4] = {t0.y, t0.w, t1.y, t1.w};
        for (int r = 0; r < 4; ++r) {
          const float v = acc[mt][nt][r];
          float p = __shfl_xor(v, 1, 64);
          p = __builtin_bit_cast(float, __builtin_bit_cast(unsigned int, p) ^ sgn);
          const float res = fmaf(p, sn[r], v * cs[r]);
          dst[((size_t)bh * SS + mrow + r) * DD + d] = f2bf(res);
        }
      }
    }
  } else {
    for (int nt = 0; nt < 8; ++nt) {
      const int d = dloc + nt*16 + c;
      const size_t vbase = ((size_t)bh * DD + d) * SS;
      for (int mt = 0; mt < 4; ++mt) {
        const int s = (m0 & 2047) + wm + mt*16 + qd*4;
        ushort4 u;
        u.x = f2bf(acc[mt][nt][0]); u.y = f2bf(acc[mt][nt][1]);
        u.z = f2bf(acc[mt][nt][2]); u.w = f2bf(acc[mt][nt][3]);
        *(ushort4*)&Vt[vbase + s] = u;
      }
    }
  }
}

// ---------------- pass A: E = exp(S) panels (bf16, causal triangle) + row sums l_z ----------------
__global__ __launch_bounds__(256)
void k_scores(const unsigned short* __restrict__ Qr, const unsigned short* __restrict__ Kr,
              unsigned short* __restrict__ Eg, float* __restrict__ lsum) {
  __shared__ short UN[17408];   // union: As[2]+Bs[2] (32 KB) | ET 128x136 (34 KB)
  short* As0 = UN;
  short* As1 = UN + 4096;
  short* Bs0 = UN + 8192;
  short* Bs1 = UN + 12288;
  unsigned short* ET = (unsigned short*)UN;
  const int tid = threadIdx.x;
  const int bh = blockIdx.y;
  const int t = blockIdx.x;
  int zb = 0;
  while (((zb + 1) * (zb + 2)) / 2 <= t) ++zb;
  const int st = t - (zb * (zb + 1)) / 2;
  const int z0 = zb * 128, s0 = st * 128;
  const int wave = tid >> 6, lane = tid & 63, qd = lane >> 4, c = lane & 15;
  const int wm = (wave >> 1) * 64, wn = (wave & 1) * 64;
  const size_t qb = (size_t)bh * SS * DD;
  floatx4 acc[4][4] = {};
  const int e0 = tid * 8, e1 = e0 + 2048;
  const int r0 = e0 >> 5, c0 = e0 & 31, r1 = e1 >> 5, c1 = e1 & 31;
  for (int k0 = 0; k0 < 512; k0 += 64) {
    __syncthreads();
    async16(&Qr[qb + (size_t)(z0 + r0) * 512 + k0      + c0], &As0[e0]);
    async16(&Qr[qb + (size_t)(z0 + r1) * 512 + k0      + c1], &As0[e1]);
    async16(&Qr[qb + (size_t)(z0 + r0) * 512 + k0 + 32 + c0], &As1[e0]);
    async16(&Qr[qb + (size_t)(z0 + r1) * 512 + k0 + 32 + c1], &As1[e1]);
    async16(&Kr[qb + (size_t)(s0 + r0) * 512 + k0      + c0], &Bs0[e0]);
    async16(&Kr[qb + (size_t)(s0 + r1) * 512 + k0      + c1], &Bs0[e1]);
    async16(&Kr[qb + (size_t)(s0 + r0) * 512 + k0 + 32 + c0], &Bs1[e0]);
    async16(&Kr[qb + (size_t)(s0 + r1) * 512 + k0 + 32 + c1], &Bs1[e1]);
    __syncthreads();
    for (int kc = 0; kc < 2; ++kc) {
      const short* Asp = kc ? As1 : As0;
      const short* Bsp = kc ? Bs1 : Bs0;
      short8v a[4], bfr[4];
      for (int mt = 0; mt < 4; ++mt) a[mt]   = *(const short8v*)&Asp[(wm + mt*16 + c)*32 + qd*8];
      for (int nt = 0; nt < 4; ++nt) bfr[nt] = *(const short8v*)&Bsp[(wn + nt*16 + c)*32 + qd*8];
      for (int mt = 0; mt < 4; ++mt)
        for (int nt = 0; nt < 4; ++nt)
          acc[mt][nt] = __builtin_amdgcn_mfma_f32_16x16x32_bf16(a[mt], bfr[nt], acc[mt][nt], 0, 0, 0);
    }
  }
  const bool diag = (st == zb);
  for (int mt = 0; mt < 4; ++mt) {
    const int zl = wm + mt*16 + qd*4;
    float rs[4] = {0.f, 0.f, 0.f, 0.f};
    for (int nt = 0; nt < 4; ++nt) {
      const int sl = wn + nt*16 + c;
      for (int r = 0; r < 4; ++r) {
        float ev = __expf(acc[mt][nt][r]);
        if (diag && (sl > zl + r)) ev = 0.f;
        acc[mt][nt][r] = ev;
        rs[r] += ev;
      }
    }
    for (int off = 1; off < 16; off <<= 1)
      for (int r = 0; r < 4; ++r) rs[r] += __shfl_xor(rs[r], off, 64);
    if (c == 0)
      for (int r = 0; r < 4; ++r)
        atomicAdd(&lsum[(size_t)bh * SS + z0 + zl + r], rs[r]);
  }
  __syncthreads();
  for (int mt = 0; mt < 4; ++mt) {
    const int zl = wm + mt*16 + qd*4;
    for (int nt = 0; nt < 4; ++nt) {
      const int sl = wn + nt*16 + c;
      ushort4 u;
      u.x = f2bf(acc[mt][nt][0]); u.y = f2bf(acc[mt][nt][1]);
      u.z = f2bf(acc[mt][nt][2]); u.w = f2bf(acc[mt][nt][3]);
      *(ushort4*)&ET[sl * 136 + zl] = u;
    }
  }
  __syncthreads();
  const size_t tb = ((size_t)bh * NTILE + t) * 16384;
  for (int it = 0; it < 8; ++it) {
    const int e = it * 2048 + tid * 8;
    const int row = e >> 7, col = e & 127;
    *(short8v*)&Eg[tb + row * 128 + col] = *(const short8v*)&ET[row * 136 + col];
  }
}

// ---------------- scale V by 1/l_z in place: Vs[d][z] = V^T[d][z] / l[z] ----------------
__global__ void k_vscale(unsigned short* __restrict__ Vt, const float* __restrict__ lsum) {
  const int idx = (blockIdx.x * 256 + threadIdx.x) * 8;
  const int z = idx & (SS - 1);
  const int bh = idx >> 20;
  short8v v = *(const short8v*)&Vt[idx];
  const float* lp = &lsum[(size_t)bh * SS + z];
  short8v o;
  for (int i = 0; i < 8; ++i)
    o[i] = (short)f2bf(bf2f((unsigned short)v[i]) / lp[i]);
  *(short8v*)&Vt[idx] = o;
}

// ---------------- pass B: out^T(128d x 128s) = sum_z Vs^T(d,z) E^T(s,z) — pure GEMM ----------------
__global__ __launch_bounds__(256)
void k_pv(const unsigned short* __restrict__ Eg, const unsigned short* __restrict__ Vs,
          unsigned short* __restrict__ Ocat) {
  __shared__ short Vl[2][128*32];
  __shared__ short El[2][128*32];
  const int tid = threadIdx.x;
  const int d0 = blockIdx.x * 128;
  const int st = blockIdx.y;          // s-tile of 128 (long blocks st=0 dispatch first per bh)
  const int bh = blockIdx.z;
  const int s0 = st * 128;
  const int bat = bh >> 3, h = bh & 7;
  const int wave = tid >> 6, lane = tid & 63, qd = lane >> 4, c = lane & 15;
  const int wm = (wave >> 1) * 64, wn = (wave & 1) * 64;
  const size_t vbb = (size_t)bh * DD * SS;
  floatx4 acc[4][4] = {};
  const int e = tid * 8;
  for (int zb = st; zb < 16; ++zb) {
    const size_t tb = ((size_t)bh * NTILE + (zb * (zb + 1)) / 2 + st) * 16384;
    for (int half = 0; half < 2; ++half) {
      const int zbase = zb * 128 + half * 64;
      __syncthreads();
      for (int i = 0; i < 4; ++i) {
        const int ee = e + i * 2048;
        const int kc = ee >> 12, row = (ee >> 5) & 127, col = ee & 31;
        async16(&Vs[vbb + (size_t)(d0 + row) * SS + zbase + kc * 32 + col], &Vl[kc][row * 32 + col]);
      }
      for (int i = 0; i < 4; ++i) {
        const int ee = e + i * 2048;
        const int kc = ee >> 12, row = (ee >> 5) & 127, col = ee & 31;
        async16(&Eg[tb + (size_t)row * 128 + half * 64 + kc * 32 + col], &El[kc][row * 32 + col]);
      }
      __syncthreads();
      for (int kc = 0; kc < 2; ++kc) {
        short8v a[4], b[4];
        for (int dt = 0; dt < 4; ++dt) a[dt] = *(const short8v*)&Vl[kc][(wm + dt*16 + c)*32 + qd*8];
        for (int nt = 0; nt < 4; ++nt) b[nt] = *(const short8v*)&El[kc][(wn + nt*16 + c)*32 + qd*8];
        for (int dt = 0; dt < 4; ++dt)
          for (int nt = 0; nt < 4; ++nt)
            acc[dt][nt] = __builtin_amdgcn_mfma_f32_16x16x32_bf16(a[dt], b[nt], acc[dt][nt], 0, 0, 0);
      }
    }
  }
  for (int nt = 0; nt < 4; ++nt) {
    const int sg = s0 + wn + nt*16 + c;
    const size_t ob = ((size_t)(bat * SS + sg)) * BHD + (size_t)h * DD + d0;
    for (int dt = 0; dt < 4; ++dt) {
      const int dloc = wm + dt*16 + qd*4;
      ushort4 u;
      u.x = f2bf(acc[dt][nt][0]); u.y = f2bf(acc[dt][nt][1]);
      u.z = f2bf(acc[dt][nt][2]); u.w = f2bf(acc[dt][nt][3]);
      *(ushort4*)&Ocat[ob + dloc] = u;
    }
  }
}

// ---------------- GEMM4: out += Ocat @ Wo, 128x128 tile, split-K=4, BK=64, f32 atomics ----------------
__global__ __launch_bounds__(256)
void k_oproj(const unsigned short* __restrict__ Ocat, const unsigned short* __restrict__ Wot,
             float* __restrict__ out) {
  __shared__ short As[2][128*32];
  __shared__ short Bs[2][128*32];
  const int tid = threadIdx.x;
  const int m0 = blockIdx.x * 128;
  const int n0 = blockIdx.y * 128;
  const int ks = blockIdx.z * 1024;
  const int wave = tid >> 6, lane = tid & 63, qd = lane >> 4, c = lane & 15;
  const int wm = (wave >> 1) * 64, wn = (wave & 1) * 64;
  floatx4 acc[4][4] = {};
  const int e0 = tid * 8, e1 = e0 + 2048;
  const int r0 = e0 >> 5, c0 = e0 & 31, r1 = e1 >> 5, c1 = e1 & 31;
  for (int k0 = ks; k0 < ks + 1024; k0 += 64) {
    __syncthreads();
    for (int kc = 0; kc < 2; ++kc) {
      const int kk = k0 + kc * 32;
      async16(&Ocat[(size_t)(m0 + r0) * BHD + kk + c0], &As[kc][e0]);
      async16(&Ocat[(size_t)(m0 + r1) * BHD + kk + c1], &As[kc][e1]);
      async16(&Wot [(size_t)(n0 + r0) * BHD + kk + c0], &Bs[kc][e0]);
      async16(&Wot [(size_t)(n0 + r1) * BHD + kk + c1], &Bs[kc][e1]);
    }
    __syncthreads();
    for (int kc = 0; kc < 2; ++kc) {
      short8v a[4], b[4];
      for (int mt = 0; mt < 4; ++mt) a[mt] = *(const short8v*)&As[kc][(wm + mt*16 + c)*32 + qd*8];
      for (int nt = 0; nt < 4; ++nt) b[nt] = *(const short8v*)&Bs[kc][(wn + nt*16 + c)*32 + qd*8];
      for (int mt = 0; mt < 4; ++mt)
        for (int nt = 0; nt < 4; ++nt)
          acc[mt][nt] = __builtin_amdgcn_mfma_f32_16x16x32_bf16(a[mt], b[nt], acc[mt][nt], 0, 0, 0);
    }
  }
  for (int mt = 0; mt < 4; ++mt) {
    const int m = m0 + wm + mt*16 + qd*4;
    for (int nt = 0; nt < 4; ++nt) {
      const int n = n0 + wn + nt*16 + c;
      for (int r = 0; r < 4; ++r)
        atomicAdd(&out[(size_t)(m + r) * DD + n], acc[mt][nt][r]);
    }
  }
}

extern "C" void kernel_launch(void* const* d_in, const int* in_sizes, int n_in,
                              void* d_out, int out_size, void* d_ws, size_t ws_size,
                              hipStream_t stream) {
  const float* q  = (const float*)d_in[0];
  const float* Wq = (const float*)d_in[1];
  const float* Wk = (const float*)d_in[2];
  const float* Wv = (const float*)d_in[3];
  const float* Wo = (const float*)d_in[4];

  // workspace layout with lifetime-based aliasing (peak ~176 MB)
  char* base = (char*)d_ws;
  unsigned short* Eg   = (unsigned short*)base;                       // 71,303,168 B
  unsigned short* qbf  = (unsigned short*)base;                       // overlay (dies after k_qkv)
  unsigned short* Wcat = (unsigned short*)(base + 4194304);           // overlay (dies after k_qkv)
  float*          rope = (float*)(base + 16777216);                   // 4 MB overlay (dies after k_qkv)
  char* p = base + 71303168;
  unsigned short* Wot  = (unsigned short*)p; p += 4194304;
  unsigned short* Qr   = (unsigned short*)p;
  unsigned short* Ocat = (unsigned short*)p; p += 33554432;           // overlays Qr (dead after k_scores)
  unsigned short* Kr   = (unsigned short*)p; p += 33554432;
  unsigned short* Vt   = (unsigned short*)p; p += 33554432;
  float*          lsum = (float*)p;

  hipMemsetAsync(lsum, 0, (size_t)NBH * SS * 4, stream);
  hipMemsetAsync(d_out, 0, (size_t)NTOK * DD * 4, stream);

  k_convert_q<<<NTOK*DD/1024, 256, 0, stream>>>(q, qbf);
  k_rope_tab<<<SS*256/256, 256, 0, stream>>>(rope);
  k_prep_w<<<dim3(16,16,32), dim3(32,8), 0, stream>>>(Wq, Wk, Wv, Wo, Wcat, Wot);
  k_qkv<<<dim3(32,48), 256, 0, stream>>>(qbf, Wcat, rope, Qr, Kr, Vt);
  k_scores<<<dim3(NTILE,16), 256, 0, stream>>>(Qr, Kr, Eg, lsum);
  k_vscale<<<NBH*DD*SS/(256*8), 256, 0, stream>>>(Vt, lsum);
  k_pv<<<dim3(4,16,16), 256, 0, stream>>>(Eg, Vt, Ocat);
  k_oproj<<<dim3(32,4,4), 256, 0, stream>>>(Ocat, Wot, (float*)d_out);
}

// Round 7
// 399.984 us; speedup vs baseline: 1.0725x; 1.0479x over previous
//
#include <hip/hip_runtime.h>
#include <hip/hip_bf16.h>
#include <math.h>
#include <stdint.h>

#define BB 2
#define SS 2048
#define DD 512
#define HH 8
#define NTOK (BB*SS)      // 4096 tokens
#define NQKV (3*HH*DD)    // 12288
#define BHD  (HH*DD)      // 4096
#define NBH  (BB*HH)      // 16
#define NTILE 136         // tri(16): causal 128x128 tiles per (b,h)

typedef __attribute__((ext_vector_type(8))) short short8v;
typedef __attribute__((ext_vector_type(4))) float floatx4;

__device__ __forceinline__ unsigned short f2bf(float f) {
  unsigned int u = __builtin_bit_cast(unsigned int, f);
  u = (u + 0x7FFFu + ((u >> 16) & 1u)) >> 16;   // RNE
  return (unsigned short)u;
}
__device__ __forceinline__ float bf2f(unsigned short s) {
  unsigned int u = ((unsigned int)s) << 16;
  return __builtin_bit_cast(float, u);
}
__device__ __forceinline__ void async16(const void* g, void* l) {
  __builtin_amdgcn_global_load_lds(
      (const __attribute__((address_space(1))) unsigned int*)g,
      (__attribute__((address_space(3))) unsigned int*)l, 16, 0, 0);
}

// ---------------- prep: q -> bf16 ----------------
__global__ void k_convert_q(const float* __restrict__ q, unsigned short* __restrict__ qbf) {
  int i = (blockIdx.x * 256 + threadIdx.x) * 4;
  const float4 v = *(const float4*)&q[i];
  ushort4 o;
  o.x = f2bf(v.x); o.y = f2bf(v.y); o.z = f2bf(v.z); o.w = f2bf(v.w);
  *(ushort4*)&qbf[i] = o;
}

// ---------------- prep: RoPE table rope[dpair][s] = {cos, sin} (f32) ----------------
__global__ void k_rope_tab(float* __restrict__ rope) {
  const int idx = blockIdx.x * 256 + threadIdx.x;   // dp*2048 + s
  const int dp = idx >> 11, s = idx & 2047;
  const float inv = exp2f(-13.287712379549449f * (1.0f/256.0f) * (float)dp);
  float sn, cs;
  __sincosf((float)s * inv, &sn, &cs);
  rope[(size_t)idx * 2]     = cs;
  rope[(size_t)idx * 2 + 1] = sn;
}

// ---------------- prep: transpose weights to B^T bf16 (Wq pre-scaled by 1/sqrt(512)) ----------------
__global__ void k_prep_w(const float* __restrict__ Wq, const float* __restrict__ Wk,
                         const float* __restrict__ Wv, const float* __restrict__ Wo,
                         unsigned short* __restrict__ Wcat, unsigned short* __restrict__ Wot) {
  __shared__ float t[32][33];
  const int z = blockIdx.z;
  const float* in; unsigned short* out; int inLD, outLD;
  float sc = 1.0f;
  if (z < 24) {
    int tsel = z / 8, h = z % 8;
    const float* w = (tsel == 0) ? Wq : (tsel == 1) ? Wk : Wv;
    if (tsel == 0) sc = 0.044194173824159216f;   // 1/sqrt(512) folded into Wq
    in = w + (size_t)h * DD * DD;
    out = Wcat + ((size_t)tsel * BHD + (size_t)h * DD) * DD;
    inLD = DD; outLD = DD;
  } else {
    int k = z - 24;
    in = Wo + (size_t)k * DD * DD;
    out = Wot + (size_t)k * DD;
    inLD = DD; outLD = BHD;
  }
  const int tx = threadIdx.x, ty = threadIdx.y;
  const int bx = blockIdx.x * 32, by = blockIdx.y * 32;
  for (int kk = 0; kk < 4; ++kk)
    t[ty + 8*kk][tx] = in[(size_t)(by + ty + 8*kk) * inLD + bx + tx];
  __syncthreads();
  for (int kk = 0; kk < 4; ++kk)
    out[(size_t)(bx + ty + 8*kk) * outLD + by + tx] = f2bf(t[tx][ty + 8*kk] * sc);
}

// ---------------- GEMM1: QKV projection, 128x256 tile (32 MFMA/wave/barrier), table-RoPE epilogue ----------------
__global__ __launch_bounds__(256, 2)
void k_qkv(const unsigned short* __restrict__ Abf, const unsigned short* __restrict__ Bt,
           const float* __restrict__ rope,
           unsigned short* __restrict__ Qr, unsigned short* __restrict__ Kr,
           unsigned short* __restrict__ Vt) {
  __shared__ short As[128*32];   //  8 KB
  __shared__ short Bs[256*32];   // 16 KB
  const int tid = threadIdx.x;
  const int m0 = blockIdx.x * 128;
  const int n0 = blockIdx.y * 256;
  const int wave = tid >> 6, lane = tid & 63, qd = lane >> 4, c = lane & 15;
  const int wm = (wave >> 1) * 64, wn = (wave & 1) * 128;
  floatx4 acc[4][8] = {};
  const int e0 = tid * 8;
  const int r0 = e0 >> 5, c0 = e0 & 31;   // r0 in [0,64)
  for (int k0 = 0; k0 < 512; k0 += 32) {
    __syncthreads();
    async16(&Abf[(size_t)(m0 + r0      ) * 512 + k0 + c0], &As[e0]);
    async16(&Abf[(size_t)(m0 + r0 +  64) * 512 + k0 + c0], &As[e0 + 2048]);
    async16(&Bt [(size_t)(n0 + r0      ) * 512 + k0 + c0], &Bs[e0]);
    async16(&Bt [(size_t)(n0 + r0 +  64) * 512 + k0 + c0], &Bs[e0 + 2048]);
    async16(&Bt [(size_t)(n0 + r0 + 128) * 512 + k0 + c0], &Bs[e0 + 4096]);
    async16(&Bt [(size_t)(n0 + r0 + 192) * 512 + k0 + c0], &Bs[e0 + 6144]);
    __syncthreads();
    short8v a[4], bfr[8];
    for (int mt = 0; mt < 4; ++mt) a[mt]   = *(const short8v*)&As[(wm + mt*16 + c)*32 + qd*8];
    for (int nt = 0; nt < 8; ++nt) bfr[nt] = *(const short8v*)&Bs[(wn + nt*16 + c)*32 + qd*8];
    for (int mt = 0; mt < 4; ++mt)
      for (int nt = 0; nt < 8; ++nt)
        acc[mt][nt] = __builtin_amdgcn_mfma_f32_16x16x32_bf16(a[mt], bfr[nt], acc[mt][nt], 0, 0, 0);
  }
  const int tsel = n0 >> 12;
  const int h = (n0 >> 9) & 7;
  const int bat = m0 >> 11;
  const int bh = bat * HH + h;
  const int dloc = (n0 & 511) + wn;
  if (tsel < 2) {
    unsigned short* dst = (tsel == 0) ? Qr : Kr;
    for (int nt = 0; nt < 8; ++nt) {
      const int d = dloc + nt*16 + c;
      const unsigned int sgn = (d & 1) ? 0u : 0x80000000u;  // even d: res = v*cs - p*sn
      const size_t rb = (size_t)(d >> 1) * (SS * 2);
      for (int mt = 0; mt < 4; ++mt) {
        const int mrow = (m0 & 2047) + wm + mt*16 + qd*4;
        const float4 t0 = *(const float4*)&rope[rb + (size_t)mrow * 2];      // cs0,sn0,cs1,sn1
        const float4 t1 = *(const float4*)&rope[rb + (size_t)mrow * 2 + 4];  // cs2,sn2,cs3,sn3
        const float cs[4] = {t0.x, t0.z, t1.x, t1.z};
        const float sn[4] = {t0.y, t0.w, t1.y, t1.w};
        for (int r = 0; r < 4; ++r) {
          const float v = acc[mt][nt][r];
          float p = __shfl_xor(v, 1, 64);
          p = __builtin_bit_cast(float, __builtin_bit_cast(unsigned int, p) ^ sgn);
          const float res = fmaf(p, sn[r], v * cs[r]);
          dst[((size_t)bh * SS + mrow + r) * DD + d] = f2bf(res);
        }
      }
    }
  } else {
    for (int nt = 0; nt < 8; ++nt) {
      const int d = dloc + nt*16 + c;
      const size_t vbase = ((size_t)bh * DD + d) * SS;
      for (int mt = 0; mt < 4; ++mt) {
        const int s = (m0 & 2047) + wm + mt*16 + qd*4;
        ushort4 u;
        u.x = f2bf(acc[mt][nt][0]); u.y = f2bf(acc[mt][nt][1]);
        u.z = f2bf(acc[mt][nt][2]); u.w = f2bf(acc[mt][nt][3]);
        *(ushort4*)&Vt[vbase + s] = u;
      }
    }
  }
}

// ---------------- pass A: E = exp(S) panels (bf16, causal triangle) + row sums l_z ----------------
__global__ __launch_bounds__(256)
void k_scores(const unsigned short* __restrict__ Qr, const unsigned short* __restrict__ Kr,
              unsigned short* __restrict__ Eg, float* __restrict__ lsum) {
  __shared__ short UN[17408];   // union: As[2]+Bs[2] (32 KB) | ET 128x136 (34 KB)
  short* As0 = UN;
  short* As1 = UN + 4096;
  short* Bs0 = UN + 8192;
  short* Bs1 = UN + 12288;
  unsigned short* ET = (unsigned short*)UN;
  const int tid = threadIdx.x;
  const int bh = blockIdx.y;
  const int t = blockIdx.x;
  int zb = 0;
  while (((zb + 1) * (zb + 2)) / 2 <= t) ++zb;
  const int st = t - (zb * (zb + 1)) / 2;
  const int z0 = zb * 128, s0 = st * 128;
  const int wave = tid >> 6, lane = tid & 63, qd = lane >> 4, c = lane & 15;
  const int wm = (wave >> 1) * 64, wn = (wave & 1) * 64;
  const size_t qb = (size_t)bh * SS * DD;
  floatx4 acc[4][4] = {};
  const int e0 = tid * 8, e1 = e0 + 2048;
  const int r0 = e0 >> 5, c0 = e0 & 31, r1 = e1 >> 5, c1 = e1 & 31;
  for (int k0 = 0; k0 < 512; k0 += 64) {
    __syncthreads();
    async16(&Qr[qb + (size_t)(z0 + r0) * 512 + k0      + c0], &As0[e0]);
    async16(&Qr[qb + (size_t)(z0 + r1) * 512 + k0      + c1], &As0[e1]);
    async16(&Qr[qb + (size_t)(z0 + r0) * 512 + k0 + 32 + c0], &As1[e0]);
    async16(&Qr[qb + (size_t)(z0 + r1) * 512 + k0 + 32 + c1], &As1[e1]);
    async16(&Kr[qb + (size_t)(s0 + r0) * 512 + k0      + c0], &Bs0[e0]);
    async16(&Kr[qb + (size_t)(s0 + r1) * 512 + k0      + c1], &Bs0[e1]);
    async16(&Kr[qb + (size_t)(s0 + r0) * 512 + k0 + 32 + c0], &Bs1[e0]);
    async16(&Kr[qb + (size_t)(s0 + r1) * 512 + k0 + 32 + c1], &Bs1[e1]);
    __syncthreads();
    for (int kc = 0; kc < 2; ++kc) {
      const short* Asp = kc ? As1 : As0;
      const short* Bsp = kc ? Bs1 : Bs0;
      short8v a[4], bfr[4];
      for (int mt = 0; mt < 4; ++mt) a[mt]   = *(const short8v*)&Asp[(wm + mt*16 + c)*32 + qd*8];
      for (int nt = 0; nt < 4; ++nt) bfr[nt] = *(const short8v*)&Bsp[(wn + nt*16 + c)*32 + qd*8];
      for (int mt = 0; mt < 4; ++mt)
        for (int nt = 0; nt < 4; ++nt)
          acc[mt][nt] = __builtin_amdgcn_mfma_f32_16x16x32_bf16(a[mt], bfr[nt], acc[mt][nt], 0, 0, 0);
    }
  }
  const bool diag = (st == zb);
  for (int mt = 0; mt < 4; ++mt) {
    const int zl = wm + mt*16 + qd*4;
    float rs[4] = {0.f, 0.f, 0.f, 0.f};
    for (int nt = 0; nt < 4; ++nt) {
      const int sl = wn + nt*16 + c;
      for (int r = 0; r < 4; ++r) {
        float ev = __expf(acc[mt][nt][r]);
        if (diag && (sl > zl + r)) ev = 0.f;
        acc[mt][nt][r] = ev;
        rs[r] += ev;
      }
    }
    for (int off = 1; off < 16; off <<= 1)
      for (int r = 0; r < 4; ++r) rs[r] += __shfl_xor(rs[r], off, 64);
    if (c == 0)
      for (int r = 0; r < 4; ++r)
        atomicAdd(&lsum[(size_t)bh * SS + z0 + zl + r], rs[r]);
  }
  __syncthreads();
  for (int mt = 0; mt < 4; ++mt) {
    const int zl = wm + mt*16 + qd*4;
    for (int nt = 0; nt < 4; ++nt) {
      const int sl = wn + nt*16 + c;
      ushort4 u;
      u.x = f2bf(acc[mt][nt][0]); u.y = f2bf(acc[mt][nt][1]);
      u.z = f2bf(acc[mt][nt][2]); u.w = f2bf(acc[mt][nt][3]);
      *(ushort4*)&ET[sl * 136 + zl] = u;
    }
  }
  __syncthreads();
  const size_t tb = ((size_t)bh * NTILE + t) * 16384;
  for (int it = 0; it < 8; ++it) {
    const int e = it * 2048 + tid * 8;
    const int row = e >> 7, col = e & 127;
    *(short8v*)&Eg[tb + row * 128 + col] = *(const short8v*)&ET[row * 136 + col];
  }
}

// ---------------- scale V by 1/l_z in place: Vs[d][z] = V^T[d][z] / l[z] ----------------
__global__ void k_vscale(unsigned short* __restrict__ Vt, const float* __restrict__ lsum) {
  const int idx = (blockIdx.x * 256 + threadIdx.x) * 8;
  const int z = idx & (SS - 1);
  const int bh = idx >> 20;
  short8v v = *(const short8v*)&Vt[idx];
  const float* lp = &lsum[(size_t)bh * SS + z];
  short8v o;
  for (int i = 0; i < 8; ++i)
    o[i] = (short)f2bf(bf2f((unsigned short)v[i]) / lp[i]);
  *(short8v*)&Vt[idx] = o;
}

// ---------------- pass B: out^T(128d x 128s) = sum_z Vs^T(d,z) E^T(s,z) — pure GEMM ----------------
// Pair-balanced: block pr handles s-columns {pr, 15-pr} -> uniform 17 z-tiles per block,
// 512 blocks (2/CU), no causal tail.
__global__ __launch_bounds__(256)
void k_pv(const unsigned short* __restrict__ Eg, const unsigned short* __restrict__ Vs,
          unsigned short* __restrict__ Ocat) {
  __shared__ short Vl[2][128*32];
  __shared__ short El[2][128*32];
  const int tid = threadIdx.x;
  const int d0 = blockIdx.x * 128;
  const int pr = blockIdx.y;          // pair index 0..7
  const int bh = blockIdx.z;
  const int bat = bh >> 3, h = bh & 7;
  const int wave = tid >> 6, lane = tid & 63, qd = lane >> 4, c = lane & 15;
  const int wm = (wave >> 1) * 64, wn = (wave & 1) * 64;
  const size_t vbb = (size_t)bh * DD * SS;
  const int e = tid * 8;
  for (int sel = 0; sel < 2; ++sel) {
    const int st = sel ? (15 - pr) : pr;
    const int s0 = st * 128;
    floatx4 acc[4][4] = {};
    for (int zb = st; zb < 16; ++zb) {
      const size_t tb = ((size_t)bh * NTILE + (zb * (zb + 1)) / 2 + st) * 16384;
      for (int half = 0; half < 2; ++half) {
        const int zbase = zb * 128 + half * 64;
        __syncthreads();
        for (int i = 0; i < 4; ++i) {
          const int ee = e + i * 2048;
          const int kc = ee >> 12, row = (ee >> 5) & 127, col = ee & 31;
          async16(&Vs[vbb + (size_t)(d0 + row) * SS + zbase + kc * 32 + col], &Vl[kc][row * 32 + col]);
        }
        for (int i = 0; i < 4; ++i) {
          const int ee = e + i * 2048;
          const int kc = ee >> 12, row = (ee >> 5) & 127, col = ee & 31;
          async16(&Eg[tb + (size_t)row * 128 + half * 64 + kc * 32 + col], &El[kc][row * 32 + col]);
        }
        __syncthreads();
        for (int kc = 0; kc < 2; ++kc) {
          short8v a[4], b[4];
          for (int dt = 0; dt < 4; ++dt) a[dt] = *(const short8v*)&Vl[kc][(wm + dt*16 + c)*32 + qd*8];
          for (int nt = 0; nt < 4; ++nt) b[nt] = *(const short8v*)&El[kc][(wn + nt*16 + c)*32 + qd*8];
          for (int dt = 0; dt < 4; ++dt)
            for (int nt = 0; nt < 4; ++nt)
              acc[dt][nt] = __builtin_amdgcn_mfma_f32_16x16x32_bf16(a[dt], b[nt], acc[dt][nt], 0, 0, 0);
        }
      }
    }
    for (int nt = 0; nt < 4; ++nt) {
      const int sg = s0 + wn + nt*16 + c;
      const size_t ob = ((size_t)(bat * SS + sg)) * BHD + (size_t)h * DD + d0;
      for (int dt = 0; dt < 4; ++dt) {
        const int dloc = wm + dt*16 + qd*4;
        ushort4 u;
        u.x = f2bf(acc[dt][nt][0]); u.y = f2bf(acc[dt][nt][1]);
        u.z = f2bf(acc[dt][nt][2]); u.w = f2bf(acc[dt][nt][3]);
        *(ushort4*)&Ocat[ob + dloc] = u;
      }
    }
  }
}

// ---------------- GEMM4: out += Ocat @ Wo, 128x128 tile, split-K=4, BK=64, f32 atomics ----------------
__global__ __launch_bounds__(256)
void k_oproj(const unsigned short* __restrict__ Ocat, const unsigned short* __restrict__ Wot,
             float* __restrict__ out) {
  __shared__ short As[2][128*32];
  __shared__ short Bs[2][128*32];
  const int tid = threadIdx.x;
  const int m0 = blockIdx.x * 128;
  const int n0 = blockIdx.y * 128;
  const int ks = blockIdx.z * 1024;
  const int wave = tid >> 6, lane = tid & 63, qd = lane >> 4, c = lane & 15;
  const int wm = (wave >> 1) * 64, wn = (wave & 1) * 64;
  floatx4 acc[4][4] = {};
  const int e0 = tid * 8, e1 = e0 + 2048;
  const int r0 = e0 >> 5, c0 = e0 & 31, r1 = e1 >> 5, c1 = e1 & 31;
  for (int k0 = ks; k0 < ks + 1024; k0 += 64) {
    __syncthreads();
    for (int kc = 0; kc < 2; ++kc) {
      const int kk = k0 + kc * 32;
      async16(&Ocat[(size_t)(m0 + r0) * BHD + kk + c0], &As[kc][e0]);
      async16(&Ocat[(size_t)(m0 + r1) * BHD + kk + c1], &As[kc][e1]);
      async16(&Wot [(size_t)(n0 + r0) * BHD + kk + c0], &Bs[kc][e0]);
      async16(&Wot [(size_t)(n0 + r1) * BHD + kk + c1], &Bs[kc][e1]);
    }
    __syncthreads();
    for (int kc = 0; kc < 2; ++kc) {
      short8v a[4], b[4];
      for (int mt = 0; mt < 4; ++mt) a[mt] = *(const short8v*)&As[kc][(wm + mt*16 + c)*32 + qd*8];
      for (int nt = 0; nt < 4; ++nt) b[nt] = *(const short8v*)&Bs[kc][(wn + nt*16 + c)*32 + qd*8];
      for (int mt = 0; mt < 4; ++mt)
        for (int nt = 0; nt < 4; ++nt)
          acc[mt][nt] = __builtin_amdgcn_mfma_f32_16x16x32_bf16(a[mt], b[nt], acc[mt][nt], 0, 0, 0);
    }
  }
  for (int mt = 0; mt < 4; ++mt) {
    const int m = m0 + wm + mt*16 + qd*4;
    for (int nt = 0; nt < 4; ++nt) {
      const int n = n0 + wn + nt*16 + c;
      for (int r = 0; r < 4; ++r)
        atomicAdd(&out[(size_t)(m + r) * DD + n], acc[mt][nt][r]);
    }
  }
}

extern "C" void kernel_launch(void* const* d_in, const int* in_sizes, int n_in,
                              void* d_out, int out_size, void* d_ws, size_t ws_size,
                              hipStream_t stream) {
  const float* q  = (const float*)d_in[0];
  const float* Wq = (const float*)d_in[1];
  const float* Wk = (const float*)d_in[2];
  const float* Wv = (const float*)d_in[3];
  const float* Wo = (const float*)d_in[4];

  // workspace layout with lifetime-based aliasing (peak ~176 MB)
  char* base = (char*)d_ws;
  unsigned short* Eg   = (unsigned short*)base;                       // 71,303,168 B
  unsigned short* qbf  = (unsigned short*)base;                       // overlay (dies after k_qkv)
  unsigned short* Wcat = (unsigned short*)(base + 4194304);           // overlay (dies after k_qkv)
  float*          rope = (float*)(base + 16777216);                   // 4 MB overlay (dies after k_qkv)
  char* p = base + 71303168;
  unsigned short* Wot  = (unsigned short*)p; p += 4194304;
  unsigned short* Qr   = (unsigned short*)p;
  unsigned short* Ocat = (unsigned short*)p; p += 33554432;           // overlays Qr (dead after k_scores)
  unsigned short* Kr   = (unsigned short*)p; p += 33554432;
  unsigned short* Vt   = (unsigned short*)p; p += 33554432;
  float*          lsum = (float*)p;

  hipMemsetAsync(lsum, 0, (size_t)NBH * SS * 4, stream);
  hipMemsetAsync(d_out, 0, (size_t)NTOK * DD * 4, stream);

  k_convert_q<<<NTOK*DD/1024, 256, 0, stream>>>(q, qbf);
  k_rope_tab<<<SS*256/256, 256, 0, stream>>>(rope);
  k_prep_w<<<dim3(16,16,32), dim3(32,8), 0, stream>>>(Wq, Wk, Wv, Wo, Wcat, Wot);
  k_qkv<<<dim3(32,48), 256, 0, stream>>>(qbf, Wcat, rope, Qr, Kr, Vt);
  k_scores<<<dim3(NTILE,16), 256, 0, stream>>>(Qr, Kr, Eg, lsum);
  k_vscale<<<NBH*DD*SS/(256*8), 256, 0, stream>>>(Vt, lsum);
  k_pv<<<dim3(4,8,16), 256, 0, stream>>>(Eg, Vt, Ocat);
  k_oproj<<<dim3(32,4,4), 256, 0, stream>>>(Ocat, Wot, (float*)d_out);
}